// Round 1
// baseline (441.469 us; speedup 1.0000x reference)
//
#include <hip/hip_runtime.h>

// Depthwise separable 4x4 FIR blur (StyleGAN2 upfirdn2d, up=down=1, pad=(2,2)).
// x: [B,C,256,256] f32, kernel: [4,4] f32 (normalized outer product, separable).
// out: [B,C,257,257] f32.
//
// True convolution semantics: out[oh,ow] = sum_{i,j} k2d[i][j] * x[oh+1-i, ow+1-j]
// Separable: k2d[i][j] = v[i]*w[j] with w[j]=k2d[0][j], v[i]=k2d[i][0]/k2d[0][0].
//
// One thread per (plane, output column). Vertical reuse kept in a 4-register
// ring of horizontally-filtered row values; horizontal overlap served by L1.

#define IW 256
#define IH 256
#define OW 257
#define OH 257

__global__ __launch_bounds__(256) void blur_fir_kernel(
    const float* __restrict__ x,
    const float* __restrict__ k2d,
    float* __restrict__ out,
    int nplanes)
{
    int g = blockIdx.x * 256 + threadIdx.x;      // task = plane*257 + ox
    int plane = g / OW;
    int ox = g - plane * OW;                     // 0..256
    if (plane >= nplanes) return;

    // Separable factors (exact: k2d entries are n/64, k2d[0]=1/64).
    float w0 = k2d[0], w1 = k2d[1], w2 = k2d[2], w3 = k2d[3];
    float inv = 1.0f / w0;
    float v1 = k2d[4] * inv;
    float v2 = k2d[8] * inv;
    float v3 = k2d[12] * inv;                    // v0 == 1

    // Column validity (input col = ox+1, ox, ox-1, ox-2; valid range [0,256))
    bool cp1 = (ox + 1 < IW);
    bool c0  = (ox     < IW);
    bool cm1 = (ox     >= 1);
    bool cm2 = (ox     >= 2);

    const float* xp = x + ((size_t)plane << 16); // plane*256*256

    auto hfilt = [&](int r) -> float {
        const float* row = xp + (r << 8);        // r*256
        float a = cp1 ? row[ox + 1] : 0.0f;
        float b = c0  ? row[ox    ] : 0.0f;
        float c = cm1 ? row[ox - 1] : 0.0f;
        float d = cm2 ? row[ox - 2] : 0.0f;
        return w0 * a + w1 * b + w2 * c + w3 * d;
    };

    // Ring: hm2=h[oh-2], hm1=h[oh-1], h0=h[oh], hp1=h[oh+1]
    float hm2 = 0.0f, hm1 = 0.0f;
    float h0  = hfilt(0);
    float hp1 = hfilt(1);

    float* op = out + (size_t)plane * (OW * OH) + ox;

    #pragma unroll 1
    for (int oh = 0; oh < OH; ++oh) {
        float res = hp1 + v1 * h0 + v2 * hm1 + v3 * hm2;  // v0==1
        *op = res;
        op += OW;
        hm2 = hm1; hm1 = h0; h0 = hp1;
        int r = oh + 2;
        hp1 = (r < IH) ? hfilt(r) : 0.0f;
    }
}

extern "C" void kernel_launch(void* const* d_in, const int* in_sizes, int n_in,
                              void* d_out, int out_size, void* d_ws, size_t ws_size,
                              hipStream_t stream) {
    const float* x   = (const float*)d_in[0];
    const float* k2d = (const float*)d_in[1];
    float* out = (float*)d_out;

    int nplanes = in_sizes[0] >> 16;             // B*C = total / (256*256)
    int ntasks  = nplanes * OW;                  // one thread per output column
    int nblocks = (ntasks + 255) / 256;

    blur_fir_kernel<<<nblocks, 256, 0, stream>>>(x, k2d, out, nplanes);
}

// Round 2
// 261.772 us; speedup vs baseline: 1.6865x; 1.6865x over previous
//
#include <hip/hip_runtime.h>

// Depthwise separable 4x4 FIR blur (StyleGAN2 upfirdn2d, up=down=1, pad=(2,2)).
// x: [B,C,256,256] f32, kernel: [4,4] f32 separable, out: [B,C,257,257] f32.
//
// out[oh,ow] = sum_{i,j} k2d[i][j] * x[oh+1-i, ow+1-j]
//            = sum_i v[i] * H[oh+1-i],  H[r][c] = sum_j w[j]*x[r][c+1-j]
// with w[j] = k2d[0][j], v[i] = k2d[i][0]/k2d[0][0]  (v0 == 1).
//
// Thread = (plane, column-group of 4, row-strip of 64). Per input row, the
// 7-float window for 4 outputs is loaded as float2 + float4 + scalar (all
// in-bounds via clamped offsets, edges zeroed by mask multiplies). Vertical
// reuse in a 4-deep register ring of float4. Column 256 via a scalar ring,
// stored only by the last lane of each group-of-64.

#define IW 256
#define IH 256
#define OW 257
#define OH 257
#define SR 64
#define NS ((OH + SR - 1) / SR)   // 5 strips per plane

typedef float f4u __attribute__((vector_size(16), aligned(4)));  // unaligned-ok store

__global__ __launch_bounds__(256) void blur_fir_kernel(
    const float* __restrict__ x,
    const float* __restrict__ k2d,
    float* __restrict__ out,
    int nplanes)
{
    const int tid = threadIdx.x;
    const int cg  = tid & 63;                      // column group: cols [4cg, 4cg+4)
    const int gs  = blockIdx.x * 4 + (tid >> 6);   // plane*NS + strip
    const int plane = gs / NS;
    const int strip = gs - plane * NS;
    if (plane >= nplanes) return;

    const float w0 = k2d[0], w1 = k2d[1], w2 = k2d[2], w3 = k2d[3];
    const float inv = 1.0f / w0;
    const float v1 = k2d[4] * inv, v2 = k2d[8] * inv, v3 = k2d[12] * inv;

    const int c0 = cg << 2;
    const float mL = (cg > 0)  ? 1.0f : 0.0f;      // cols c0-2,c0-1 valid?
    const float mR = (cg < 63) ? 1.0f : 0.0f;      // col c0+4 valid?
    const int offL = (cg > 0)  ? (c0 - 2) : 0;     // clamped, always in-bounds
    const int offR = (cg < 63) ? (c0 + 4) : 0;

    const float* xp = x + ((size_t)plane << 16);

    const int r0 = strip * SR;
    const int nrows = min(SR, OH - r0);

    auto loadrow = [&](int r, float2& L, float4& Bv, float& Rv, float& rm) {
        rm = (r >= 0 && r < IH) ? 1.0f : 0.0f;
        int rr = min(max(r, 0), IH - 1);
        const float* row = xp + (rr << 8);
        L  = *(const float2*)(row + offL);         // 8B aligned
        Bv = *(const float4*)(row + c0);           // 16B aligned
        Rv = row[offR];
    };
    auto hcomb = [&](float2 L, float4 Bv, float Rv, float rm, float4& h, float& h4) {
        float lx = L.x * mL, ly = L.y * mL;
        float rv = Rv * mR;
        h.x = w0 * Bv.y + w1 * Bv.x + w2 * ly   + w3 * lx;
        h.y = w0 * Bv.z + w1 * Bv.y + w2 * Bv.x + w3 * ly;
        h.z = w0 * Bv.w + w1 * Bv.z + w2 * Bv.y + w3 * Bv.x;
        h.w = w0 * rv   + w1 * Bv.w + w2 * Bv.z + w3 * Bv.y;
        h4  = w2 * Bv.w + w3 * Bv.z;               // out col 256 (x[256],x[257] OOB -> 0)
        h.x *= rm; h.y *= rm; h.z *= rm; h.w *= rm; h4 *= rm;
    };
    auto hfilt = [&](int r, float4& h, float& h4) {
        float2 L; float4 Bv; float Rv, rm;
        loadrow(r, L, Bv, Rv, rm);
        hcomb(L, Bv, Rv, rm, h, h4);
    };

    // Prime ring with H(r0-2)..H(r0+1)
    float4 hm2, hm1, h0, hp1;
    float  sm2, sm1, s0, sp1;
    hfilt(r0 - 2, hm2, sm2);
    hfilt(r0 - 1, hm1, sm1);
    hfilt(r0,     h0,  s0);
    hfilt(r0 + 1, hp1, sp1);

    float* op = out + (size_t)plane * (OW * OH) + (size_t)r0 * OW + c0;
    const bool last = (cg == 63);

    for (int i = 0; i < nrows; ++i) {
        // issue next input row's loads first (overlap with ring compute/store)
        float2 L; float4 Bv; float Rv, rm;
        loadrow(r0 + i + 2, L, Bv, Rv, rm);

        float4 res;
        res.x = hp1.x + v1 * h0.x + v2 * hm1.x + v3 * hm2.x;
        res.y = hp1.y + v1 * h0.y + v2 * hm1.y + v3 * hm2.y;
        res.z = hp1.z + v1 * h0.z + v2 * hm1.z + v3 * hm2.z;
        res.w = hp1.w + v1 * h0.w + v2 * hm1.w + v3 * hm2.w;
        *(f4u*)op = (f4u){res.x, res.y, res.z, res.w};
        if (last) op[4] = sp1 + v1 * s0 + v2 * sm1 + v3 * sm2;
        op += OW;

        float4 hn; float sn;
        hcomb(L, Bv, Rv, rm, hn, sn);
        hm2 = hm1; hm1 = h0; h0 = hp1; hp1 = hn;
        sm2 = sm1; sm1 = s0; s0 = sp1; sp1 = sn;
    }
}

extern "C" void kernel_launch(void* const* d_in, const int* in_sizes, int n_in,
                              void* d_out, int out_size, void* d_ws, size_t ws_size,
                              hipStream_t stream) {
    const float* x   = (const float*)d_in[0];
    const float* k2d = (const float*)d_in[1];
    float* out = (float*)d_out;

    int nplanes = in_sizes[0] >> 16;         // B*C
    int total   = nplanes * NS;              // (plane,strip) tasks; 64 lanes each
    int nblocks = (total + 3) / 4;           // 4 tasks per 256-thread block

    blur_fir_kernel<<<nblocks, 256, 0, stream>>>(x, k2d, out, nplanes);
}